// Round 2
// baseline (543.294 us; speedup 1.0000x reference)
//
#include <hip/hip_runtime.h>
#include <hip/hip_bf16.h>

#define I_N 256
#define T_N 256
#define L_N 32
#define E_N 128
#define P_N 49
#define EPAD 132   // 132 floats = 528 B = 33*16 B: float4-aligned rows, conflict-free b128

__global__ __launch_bounds__(256) void clip_match_kernel(
    const float* __restrict__ img,   // [I][E][P]
    const float* __restrict__ txt,   // [T][L][E]
    const int*   __restrict__ tlen,  // [T]
    const float* __restrict__ nlt,   // [1]
    float*       __restrict__ out)   // [I*T] logits_per_image ++ [T*I] logits_per_text
{
    __shared__ __align__(16) float simg[P_N * EPAD];

    const int i   = blockIdx.y;
    const int tg  = blockIdx.x;      // 0..63 (4 texts per block)
    const int tid = threadIdx.x;

    // Stage image i into LDS, transposed: simg[p][e]. Global reads coalesced.
    const float* gimg = img + i * (E_N * P_N);
    for (int idx = tid; idx < E_N * P_N; idx += 256) {
        int e = idx / P_N;
        int p = idx - e * P_N;
        simg[p * EPAD + e] = gimg[idx];
    }
    __syncthreads();

    // One text per wave; text reads are wave-uniform -> scalar loads.
    const int wid  = __builtin_amdgcn_readfirstlane(tid >> 6);
    const int lane = tid & 63;
    const int p    = (lane < P_N) ? lane : (P_N - 1);  // dup p=48 on tail lanes: max-safe
    const int t    = tg * 4 + wid;

    const float*  tx = txt + t * (L_N * E_N);
    const float4* av = (const float4*)(simg + p * EPAD);

    float sum = 0.0f;   // Sum over ALL 32 tokens (reference does NOT mask by length).

    for (int lg = 0; lg < 4; ++lg) {
        float acc[8];
        #pragma unroll
        for (int j = 0; j < 8; ++j) acc[j] = 0.0f;

        const float* tb = tx + (lg * 8) * E_N;

        #pragma unroll 2
        for (int e4 = 0; e4 < E_N / 4; ++e4) {
            float4 a = av[e4];
            #pragma unroll
            for (int j = 0; j < 8; ++j) {
                float4 b = *(const float4*)(tb + j * E_N + e4 * 4);
                acc[j] = fmaf(a.x, b.x, acc[j]);
                acc[j] = fmaf(a.y, b.y, acc[j]);
                acc[j] = fmaf(a.z, b.z, acc[j]);
                acc[j] = fmaf(a.w, b.w, acc[j]);
            }
        }

        #pragma unroll
        for (int j = 0; j < 8; ++j) {
            float m = acc[j];
            #pragma unroll
            for (int off = 32; off > 0; off >>= 1)
                m = fmaxf(m, __shfl_xor(m, off));
            sum += m;   // all tokens contribute; same value in every lane
        }
    }

    if (lane == 0) {
        const int len = tlen[t];
        float scale = expf(nlt[0]);
        float match = (sum / (float)len) * scale;
        out[i * T_N + t]             = match;   // logits_per_image [I][T]
        out[I_N * T_N + t * I_N + i] = match;   // logits_per_text  [T][I]
    }
}

extern "C" void kernel_launch(void* const* d_in, const int* in_sizes, int n_in,
                              void* d_out, int out_size, void* d_ws, size_t ws_size,
                              hipStream_t stream) {
    const float* img  = (const float*)d_in[0];
    const float* txt  = (const float*)d_in[1];
    const int*   tlen = (const int*)d_in[2];
    const float* nlt  = (const float*)d_in[3];
    float*       out  = (float*)d_out;

    dim3 grid(T_N / 4, I_N);
    dim3 block(256);
    clip_match_kernel<<<grid, block, 0, stream>>>(img, txt, tlen, nlt, out);
}

// Round 3
// 51.112 us; speedup vs baseline: 10.6295x; 10.6295x over previous
//
#include <hip/hip_runtime.h>
#include <hip/hip_bf16.h>

typedef __attribute__((ext_vector_type(8))) short bf16x8;
typedef __attribute__((ext_vector_type(4))) float f32x4;

#define I_N 256
#define T_N 256
#define L_N 32
#define E_N 128
#define P_N 49

// ---------------- pre-pass: pack text into B-fragment order ----------------
// B_pre[tt=512][kk=4][lane=64][8 bf16]  (2 MB). textrow = tt*16 + (lane&15),
// k = kk*32 + (lane>>4)*8 + j  (contiguous in E -> coalesced-ish fp32 reads)
__global__ __launch_bounds__(256) void pack_text(const float* __restrict__ txt,
                                                 unsigned short* __restrict__ bpre) {
    int gid  = blockIdx.x * 256 + threadIdx.x;   // 512*4*64 = 131072 threads
    int lane = gid & 63;
    int kk   = (gid >> 6) & 3;
    int tt   = gid >> 8;
    int row  = tt * 16 + (lane & 15);            // t*32 + l
    int e0   = kk * 32 + (lane >> 4) * 8;
    const float* src = txt + row * E_N + e0;
    union { unsigned short u[8]; bf16x8 v; } o;
    #pragma unroll
    for (int j = 0; j < 8; ++j) {
        __hip_bfloat16 h = __float2bfloat16(src[j]);
        o.u[j] = *reinterpret_cast<unsigned short*>(&h);
    }
    ((bf16x8*)bpre)[gid] = o.v;
}

// ---------------- pre-pass: pack image into A-fragment order ----------------
// A_pre[i=256][pt=4][kk=4][lane=64][8 bf16] (4 MB). patch = pt*16 + (lane&15),
// k(=e) = kk*32 + (lane>>4)*8 + j. patch >= 49 -> 0 (masked out of max later).
__global__ __launch_bounds__(256) void pack_img(const float* __restrict__ img,
                                                unsigned short* __restrict__ apre) {
    int gid   = blockIdx.x * 256 + threadIdx.x;  // 256*4*4*64 = 262144 threads
    int lane  = gid & 63;
    int kk    = (gid >> 6) & 3;
    int pt    = (gid >> 8) & 3;
    int i     = gid >> 10;
    int patch = pt * 16 + (lane & 15);
    int e0    = kk * 32 + (lane >> 4) * 8;
    const float* src = img + i * (E_N * P_N) + e0 * P_N + patch;
    union { unsigned short u[8]; bf16x8 v; } o;
    #pragma unroll
    for (int j = 0; j < 8; ++j) {
        float x = (patch < P_N) ? src[j * P_N] : 0.0f;
        __hip_bfloat16 h = __float2bfloat16(x);
        o.u[j] = *reinterpret_cast<unsigned short*>(&h);
    }
    ((bf16x8*)apre)[gid] = o.v;
}

// ---------------- main kernel ----------------
// grid (4, 256): blockIdx.y = image, blockIdx.x = text-group of 64.
// 4 waves/block, 16 texts per wave. Image A-frags pinned in registers.
__global__ __launch_bounds__(256) void clip_mfma(
    const unsigned short* __restrict__ apre,
    const unsigned short* __restrict__ bpre,
    const int*   __restrict__ tlen,
    const float* __restrict__ nlt,
    float*       __restrict__ out) {

    const int i    = blockIdx.y;
    const int wid  = threadIdx.x >> 6;
    const int lane = threadIdx.x & 63;
    const int t0   = blockIdx.x * 64 + wid * 16;
    const float scale = expf(nlt[0]);
    const bool  lo16  = (lane < 16);   // lane-group 0: holds patch 48 in pt=3, reg 0

    // Load the image's 16 A-frags (64 VGPRs), reused for all 64 texts.
    const bf16x8* ap = (const bf16x8*)apre + (size_t)i * 16 * 64;
    bf16x8 af[4][4];   // [pt][kk]
    #pragma unroll
    for (int pt = 0; pt < 4; ++pt)
        #pragma unroll
        for (int kk = 0; kk < 4; ++kk)
            af[pt][kk] = ap[(pt * 4 + kk) * 64 + lane];

    const bf16x8* bp = (const bf16x8*)bpre;

    auto loadB = [&](int t, bf16x8 (&bf)[2][4]) {
        #pragma unroll
        for (int ctt = 0; ctt < 2; ++ctt)
            #pragma unroll
            for (int kk = 0; kk < 4; ++kk)
                bf[ctt][kk] = bp[((t * 2 + ctt) * 4 + kk) * 64 + lane];
    };

    auto computeT = [&](int t, bf16x8 (&bf)[2][4]) {
        f32x4 acc[4][2];
        #pragma unroll
        for (int pt = 0; pt < 4; ++pt)
            #pragma unroll
            for (int ctt = 0; ctt < 2; ++ctt)
                acc[pt][ctt] = (f32x4){0.f, 0.f, 0.f, 0.f};

        #pragma unroll
        for (int kk = 0; kk < 4; ++kk)
            #pragma unroll
            for (int pt = 0; pt < 4; ++pt)
                #pragma unroll
                for (int ctt = 0; ctt < 2; ++ctt)
                    acc[pt][ctt] = __builtin_amdgcn_mfma_f32_16x16x32_bf16(
                        af[pt][kk], bf[ctt][kk], acc[pt][ctt], 0, 0, 0);

        // Reduce: max over patches (C rows), then sum over 32 token cols.
        // C layout: col = lane&15 (tokenrow), row = (lane>>4)*4 + reg (patch).
        float colmax[2];
        #pragma unroll
        for (int ctt = 0; ctt < 2; ++ctt) {
            float m[4];
            #pragma unroll
            for (int r = 0; r < 4; ++r)
                m[r] = fmaxf(fmaxf(acc[0][ctt][r], acc[1][ctt][r]), acc[2][ctt][r]);
            // pt=3 covers patches 48..63; only patch 48 (lane<16, reg 0) is valid.
            m[0] = fmaxf(m[0], lo16 ? acc[3][ctt][0] : -INFINITY);
            float mm = fmaxf(fmaxf(m[0], m[1]), fmaxf(m[2], m[3]));
            mm = fmaxf(mm, __shfl_xor(mm, 16));
            mm = fmaxf(mm, __shfl_xor(mm, 32));
            colmax[ctt] = mm;   // max over all 49 patches for tokenrow (lane&15)
        }
        float s = colmax[0] + colmax[1];       // tokens l and l+16
        #pragma unroll
        for (int off = 1; off <= 8; off <<= 1)
            s += __shfl_xor(s, off);           // sum over the 16 token columns

        if (lane == 0) {
            float match = (s / (float)tlen[t]) * scale;
            out[i * T_N + t]             = match;  // logits_per_image [I][T]
            out[I_N * T_N + t * I_N + i] = match;  // logits_per_text  [T][I]
        }
    };

    // Ping-pong over 16 texts: overlap next B-frag loads with current compute.
    bf16x8 bufA[2][4], bufB[2][4];
    loadB(t0, bufA);
    #pragma unroll 1
    for (int tx = 0; tx < 16; tx += 2) {
        loadB(t0 + tx + 1, bufB);
        computeT(t0 + tx, bufA);
        if (tx + 2 < 16) loadB(t0 + tx + 2, bufA);
        computeT(t0 + tx + 1, bufB);
    }
}

extern "C" void kernel_launch(void* const* d_in, const int* in_sizes, int n_in,
                              void* d_out, int out_size, void* d_ws, size_t ws_size,
                              hipStream_t stream) {
    const float* img  = (const float*)d_in[0];
    const float* txt  = (const float*)d_in[1];
    const int*   tlen = (const int*)d_in[2];
    const float* nlt  = (const float*)d_in[3];
    float*       out  = (float*)d_out;

    unsigned short* bpre = (unsigned short*)d_ws;                    // 2 MB
    unsigned short* apre = (unsigned short*)((char*)d_ws + (2u << 20)); // 4 MB

    pack_text<<<512, 256, 0, stream>>>(txt, bpre);
    pack_img<<<1024, 256, 0, stream>>>(img, apre);

    dim3 grid(4, I_N);
    clip_mfma<<<grid, 256, 0, stream>>>(apre, bpre, tlen, nlt, out);
}

// Round 4
// 47.317 us; speedup vs baseline: 11.4820x; 1.0802x over previous
//
#include <hip/hip_runtime.h>
#include <hip/hip_bf16.h>

typedef __attribute__((ext_vector_type(8))) short bf16x8;
typedef __attribute__((ext_vector_type(4))) float f32x4;

#define I_N 256
#define T_N 256
#define L_N 32
#define E_N 128
#define P_N 49
#define TG  4   // texts per LDS buffer (4 texts * 8 frags * 1KB = 32 KB/buffer)

// ---------------- pre-pass: pack text + image into MFMA fragment order ------
// bpre frag layout: [t*8 + ctt*4 + kk][lane][8 bf16]; tokenrow = (t*2+ctt)*16+(lane&15),
// k(e) = kk*32 + (lane>>4)*8 + j.
// apre frag layout: [i][pt*4+kk][lane][8 bf16]; patch = pt*16+(lane&15), same k map.
__global__ __launch_bounds__(256) void pack_all(const float* __restrict__ txt,
                                                const float* __restrict__ img,
                                                unsigned short* __restrict__ bpre,
                                                unsigned short* __restrict__ apre) {
    const int bid = blockIdx.x;
    if (bid < 512) {                       // ---- text ----
        int gid  = bid * 256 + threadIdx.x;        // 512*256 = 131072
        int lane = gid & 63;
        int kk   = (gid >> 6) & 3;
        int tt   = gid >> 8;                       // 0..511 = t*2+ctt
        int row  = tt * 16 + (lane & 15);          // t*32 + l
        int e0   = kk * 32 + (lane >> 4) * 8;
        const float* src = txt + row * E_N + e0;
        union { unsigned short u[8]; bf16x8 v; } o;
        #pragma unroll
        for (int j = 0; j < 8; ++j) {
            __hip_bfloat16 h = __float2bfloat16(src[j]);
            o.u[j] = *reinterpret_cast<unsigned short*>(&h);
        }
        ((bf16x8*)bpre)[gid] = o.v;
    } else {                               // ---- image ----
        int gid   = (bid - 512) * 256 + threadIdx.x;  // 1024*256 = 262144
        int lane  = gid & 63;
        int kk    = (gid >> 6) & 3;
        int pt    = (gid >> 8) & 3;
        int i     = gid >> 10;
        int patch = pt * 16 + (lane & 15);
        int e0    = kk * 32 + (lane >> 4) * 8;
        const float* src = img + i * (E_N * P_N) + e0 * P_N + patch;
        union { unsigned short u[8]; bf16x8 v; } o;
        #pragma unroll
        for (int j = 0; j < 8; ++j) {
            float x = (patch < P_N) ? src[j * P_N] : 0.0f;
            __hip_bfloat16 h = __float2bfloat16(x);
            o.u[j] = *reinterpret_cast<unsigned short*>(&h);
        }
        ((bf16x8*)apre)[gid] = o.v;
    }
}

// ---------------- main kernel ----------------
// grid (16, 32), block 512 = 8 waves. Wave w -> image blockIdx.y*8+w.
// Block covers texts t0..t0+15; B-frags staged in LDS once, shared by all 8 waves.
__global__ __launch_bounds__(512) void clip_mfma(
    const unsigned short* __restrict__ apre,
    const unsigned short* __restrict__ bpre,
    const int*   __restrict__ tlen,
    const float* __restrict__ nlt,
    float*       __restrict__ out) {

    __shared__ short sB[2][TG * 8 * 64 * 8];   // 2 x 32 KB

    const int wid  = threadIdx.x >> 6;
    const int lane = threadIdx.x & 63;
    const int i    = blockIdx.y * 8 + wid;
    const int t0   = blockIdx.x * 16;
    const float scale = expf(nlt[0]);
    const bool  lo16  = (lane < 16);

    // Pin this wave's image A-frags in registers (64 VGPRs), reused for all 16 texts.
    bf16x8 af[4][4];
    const bf16x8* ap = (const bf16x8*)apre + (size_t)i * 16 * 64;
    #pragma unroll
    for (int pt = 0; pt < 4; ++pt)
        #pragma unroll
        for (int kk = 0; kk < 4; ++kk)
            af[pt][kk] = ap[(pt * 4 + kk) * 64 + lane];

    // Stage B-frags for texts [t0+g*TG, +TG) into sB[buf]. 32 frags; wave w does 4.
    // global_load_lds: per-lane global src, wave-uniform LDS base (+lane*16 by HW).
    auto stage = [&](int buf, int g) {
        #pragma unroll
        for (int q = 0; q < 4; ++q) {
            int fl = wid * 4 + q;                       // 0..31 = tx*8 + f
            int t  = t0 + g * TG + (fl >> 3);
            int f  = fl & 7;
            const unsigned short* src = bpre + ((size_t)(t * 8 + f)) * 512 + lane * 8;
            short* dst = &sB[buf][fl * 512];
            __builtin_amdgcn_global_load_lds(
                (const __attribute__((address_space(1))) unsigned int*)(const void*)src,
                (__attribute__((address_space(3))) unsigned int*)(void*)dst, 16, 0, 0);
        }
    };

    stage(0, 0);
    __syncthreads();   // drains vmcnt before barrier (compiler semantics)

    #pragma unroll 1
    for (int g = 0; g < 4; ++g) {
        const int cur = g & 1;
        if (g < 3) stage(cur ^ 1, g + 1);   // prefetch next group, other buffer

        const bf16x8* bfp = (const bf16x8*)&sB[cur][0];
        #pragma unroll
        for (int tx = 0; tx < TG; ++tx) {
            bf16x8 bf[2][4];
            #pragma unroll
            for (int ctt = 0; ctt < 2; ++ctt)
                #pragma unroll
                for (int kk = 0; kk < 4; ++kk)
                    bf[ctt][kk] = bfp[(tx * 8 + ctt * 4 + kk) * 64 + lane];

            f32x4 acc[4][2];
            #pragma unroll
            for (int pt = 0; pt < 4; ++pt)
                #pragma unroll
                for (int ctt = 0; ctt < 2; ++ctt)
                    acc[pt][ctt] = (f32x4){0.f, 0.f, 0.f, 0.f};

            #pragma unroll
            for (int kk = 0; kk < 4; ++kk)
                #pragma unroll
                for (int pt = 0; pt < 4; ++pt)
                    #pragma unroll
                    for (int ctt = 0; ctt < 2; ++ctt)
                        acc[pt][ctt] = __builtin_amdgcn_mfma_f32_16x16x32_bf16(
                            af[pt][kk], bf[ctt][kk], acc[pt][ctt], 0, 0, 0);

            // Reduce: max over patches (C rows), sum over 32 token cols.
            // C layout: col = lane&15 (tokenrow), row = (lane>>4)*4 + reg (patch).
            float colmax[2];
            #pragma unroll
            for (int ctt = 0; ctt < 2; ++ctt) {
                float m[4];
                #pragma unroll
                for (int r = 0; r < 4; ++r)
                    m[r] = fmaxf(fmaxf(acc[0][ctt][r], acc[1][ctt][r]), acc[2][ctt][r]);
                // pt=3 covers patches 48..63; only patch 48 (lane<16, reg 0) valid.
                m[0] = fmaxf(m[0], lo16 ? acc[3][ctt][0] : -INFINITY);
                float mm = fmaxf(fmaxf(m[0], m[1]), fmaxf(m[2], m[3]));
                mm = fmaxf(mm, __shfl_xor(mm, 16));
                mm = fmaxf(mm, __shfl_xor(mm, 32));
                colmax[ctt] = mm;
            }
            float s = colmax[0] + colmax[1];
            #pragma unroll
            for (int off = 1; off <= 8; off <<= 1)
                s += __shfl_xor(s, off);

            const int t = t0 + g * TG + tx;
            if (lane == 0) {
                float match = (s / (float)tlen[t]) * scale;
                out[i * T_N + t]             = match;  // logits_per_image [I][T]
                out[I_N * T_N + t * I_N + i] = match;  // logits_per_text  [T][I]
            }
        }
        __syncthreads();   // staged loads complete; all waves done with buf cur
    }
}

extern "C" void kernel_launch(void* const* d_in, const int* in_sizes, int n_in,
                              void* d_out, int out_size, void* d_ws, size_t ws_size,
                              hipStream_t stream) {
    const float* img  = (const float*)d_in[0];
    const float* txt  = (const float*)d_in[1];
    const int*   tlen = (const int*)d_in[2];
    const float* nlt  = (const float*)d_in[3];
    float*       out  = (float*)d_out;

    unsigned short* bpre = (unsigned short*)d_ws;                       // 2 MB
    unsigned short* apre = (unsigned short*)((char*)d_ws + (2u << 20)); // 4 MB

    pack_all<<<1536, 256, 0, stream>>>(txt, img, bpre, apre);

    dim3 grid(16, 32);
    clip_mfma<<<grid, 512, 0, stream>>>(apre, bpre, tlen, nlt, out);
}

// Round 5
// 45.538 us; speedup vs baseline: 11.9307x; 1.0391x over previous
//
#include <hip/hip_runtime.h>
#include <hip/hip_bf16.h>

typedef __attribute__((ext_vector_type(8))) short bf16x8;
typedef __attribute__((ext_vector_type(4))) float f32x4;

#define I_N 256
#define T_N 256
#define L_N 32
#define E_N 128
#define P_N 49
#define TG  4   // texts per LDS buffer (4 texts * 8 frags * 1KB = 32 KB/buffer)

// ---------------- pre-pass: pack text + image into MFMA fragment order ------
// bpre frag layout: [t*8 + ctt*4 + kk][lane][8 bf16]; tokenrow = (t*2+ctt)*16+(lane&15),
// k(e) = kk*32 + (lane>>4)*8 + j.
// apre frag layout: [i][pt*4+kk][lane][8 bf16]; patch = pt*16+(lane&15), same k map.
__global__ __launch_bounds__(256) void pack_all(const float* __restrict__ txt,
                                                const float* __restrict__ img,
                                                unsigned short* __restrict__ bpre,
                                                unsigned short* __restrict__ apre) {
    const int bid = blockIdx.x;
    if (bid < 512) {                       // ---- text ----
        int gid  = bid * 256 + threadIdx.x;        // 512*256 = 131072
        int lane = gid & 63;
        int kk   = (gid >> 6) & 3;
        int tt   = gid >> 8;                       // 0..511 = t*2+ctt
        int row  = tt * 16 + (lane & 15);          // t*32 + l
        int e0   = kk * 32 + (lane >> 4) * 8;
        const float* src = txt + row * E_N + e0;
        union { unsigned short u[8]; bf16x8 v; } o;
        #pragma unroll
        for (int j = 0; j < 8; ++j) {
            __hip_bfloat16 h = __float2bfloat16(src[j]);
            o.u[j] = *reinterpret_cast<unsigned short*>(&h);
        }
        ((bf16x8*)bpre)[gid] = o.v;
    } else {                               // ---- image ----
        int gid   = (bid - 512) * 256 + threadIdx.x;  // 1024*256 = 262144
        int lane  = gid & 63;
        int kk    = (gid >> 6) & 3;
        int pt    = (gid >> 8) & 3;
        int i     = gid >> 10;
        int patch = pt * 16 + (lane & 15);
        int e0    = kk * 32 + (lane >> 4) * 8;
        const float* src = img + i * (E_N * P_N) + e0 * P_N + patch;
        union { unsigned short u[8]; bf16x8 v; } o;
        #pragma unroll
        for (int j = 0; j < 8; ++j) {
            float x = (patch < P_N) ? src[j * P_N] : 0.0f;
            __hip_bfloat16 h = __float2bfloat16(x);
            o.u[j] = *reinterpret_cast<unsigned short*>(&h);
        }
        ((bf16x8*)apre)[gid] = o.v;
    }
}

// ---------------- main kernel ----------------
// grid (16, 32), block 512 = 8 waves. Wave w -> image blockIdx.y*8+w.
// Texts t0..t0+15 per block; B-frags staged once into LDS, shared by 8 waves.
// 2-deep text pipeline: slot tx does loadB(tx)+MFMA(tx), then reduce(tx-1),
// so the serial shuffle-reduce of text tx-1 hides under tx's MFMA drain.
__global__ __launch_bounds__(512) void clip_mfma(
    const unsigned short* __restrict__ apre,
    const unsigned short* __restrict__ bpre,
    const int*   __restrict__ tlen,
    const float* __restrict__ nlt,
    float*       __restrict__ out) {

    __shared__ short sB[2][TG * 8 * 512];   // 2 x 32 KB

    const int wid  = threadIdx.x >> 6;
    const int lane = threadIdx.x & 63;
    const int i    = blockIdx.y * 8 + wid;
    const int t0   = blockIdx.x * 16;
    const float scale = expf(nlt[0]);
    const bool  lo16  = (lane < 16);

    // Pin this wave's image A-frags in registers (64 VGPRs), reused for 16 texts.
    bf16x8 af[4][4];
    const bf16x8* ap = (const bf16x8*)apre + (size_t)i * 16 * 64;
    #pragma unroll
    for (int pt = 0; pt < 4; ++pt)
        #pragma unroll
        for (int kk = 0; kk < 4; ++kk)
            af[pt][kk] = ap[(pt * 4 + kk) * 64 + lane];

    // Stage B-frags for texts [t0+g*TG, +TG) into sB[buf]. 32 frags; wave w does 4.
    auto stage = [&](int buf, int g) {
        #pragma unroll
        for (int q = 0; q < 4; ++q) {
            int fl = wid * 4 + q;                       // 0..31 = t_in_group*8 + f
            int t  = t0 + g * TG + (fl >> 3);
            int f  = fl & 7;
            const unsigned short* src = bpre + ((size_t)(t * 8 + f)) * 512 + lane * 8;
            short* dst = &sB[buf][fl * 512];
            __builtin_amdgcn_global_load_lds(
                (const __attribute__((address_space(1))) unsigned int*)(const void*)src,
                (__attribute__((address_space(3))) unsigned int*)(void*)dst, 16, 0, 0);
        }
    };

    // Reduce one text's accumulators: max over 49 patches, sum over 32 tokens.
    // C layout: col = lane&15 (tokenrow), row = (lane>>4)*4 + reg (patch).
    auto reduceT = [&](f32x4 (&a)[4][2], int t) {
        float colmax[2];
        #pragma unroll
        for (int ctt = 0; ctt < 2; ++ctt) {
            float m[4];
            #pragma unroll
            for (int r = 0; r < 4; ++r)
                m[r] = fmaxf(fmaxf(a[0][ctt][r], a[1][ctt][r]), a[2][ctt][r]);
            // pt=3 covers patches 48..63; only patch 48 (lane<16, reg 0) valid.
            m[0] = fmaxf(m[0], lo16 ? a[3][ctt][0] : -INFINITY);
            float mm = fmaxf(fmaxf(m[0], m[1]), fmaxf(m[2], m[3]));
            mm = fmaxf(mm, __shfl_xor(mm, 16));
            mm = fmaxf(mm, __shfl_xor(mm, 32));
            colmax[ctt] = mm;
        }
        float s = colmax[0] + colmax[1];
        #pragma unroll
        for (int off = 1; off <= 8; off <<= 1)
            s += __shfl_xor(s, off);
        if (lane == 0) {
            float match = (s / (float)tlen[t]) * scale;
            out[i * T_N + t]             = match;  // logits_per_image [I][T]
            out[I_N * T_N + t * I_N + i] = match;  // logits_per_text  [T][I]
        }
    };

    bf16x8 bf[2][2][4];    // [parity][ctt][kk]
    f32x4  acc[2][4][2];   // [parity][pt][ctt]

    stage(0, 0);
    __syncthreads();

    #pragma unroll
    for (int tx = 0; tx < 16; ++tx) {       // full unroll -> all indices static
        const int p   = tx & 1;
        const int gg  = tx >> 2;
        const int txg = tx & 3;

        if ((tx & 3) == 0) {
            if (tx > 0) __syncthreads();    // buf (gg&1) staged; buf (gg+1)&1 free
            if (gg + 1 < 4) stage((gg + 1) & 1, gg + 1);
        }

        const bf16x8* bfp = (const bf16x8*)&sB[gg & 1][0];
        #pragma unroll
        for (int ctt = 0; ctt < 2; ++ctt)
            #pragma unroll
            for (int kk = 0; kk < 4; ++kk)
                bf[p][ctt][kk] = bfp[(txg * 8 + ctt * 4 + kk) * 64 + lane];

        #pragma unroll
        for (int pt = 0; pt < 4; ++pt)
            #pragma unroll
            for (int ctt = 0; ctt < 2; ++ctt)
                acc[p][pt][ctt] = (f32x4){0.f, 0.f, 0.f, 0.f};

        #pragma unroll
        for (int kk = 0; kk < 4; ++kk)
            #pragma unroll
            for (int pt = 0; pt < 4; ++pt)
                #pragma unroll
                for (int ctt = 0; ctt < 2; ++ctt)
                    acc[p][pt][ctt] = __builtin_amdgcn_mfma_f32_16x16x32_bf16(
                        af[pt][kk], bf[p][ctt][kk], acc[p][pt][ctt], 0, 0, 0);

        if (tx > 0) reduceT(acc[1 - p], t0 + tx - 1);   // overlap with tx's MFMA drain
    }
    reduceT(acc[1], t0 + 15);               // tx=15 had parity 1
}

extern "C" void kernel_launch(void* const* d_in, const int* in_sizes, int n_in,
                              void* d_out, int out_size, void* d_ws, size_t ws_size,
                              hipStream_t stream) {
    const float* img  = (const float*)d_in[0];
    const float* txt  = (const float*)d_in[1];
    const int*   tlen = (const int*)d_in[2];
    const float* nlt  = (const float*)d_in[3];
    float*       out  = (float*)d_out;

    unsigned short* bpre = (unsigned short*)d_ws;                       // 2 MB
    unsigned short* apre = (unsigned short*)((char*)d_ws + (2u << 20)); // 4 MB

    pack_all<<<1536, 256, 0, stream>>>(txt, img, bpre, apre);

    dim3 grid(16, 32);
    clip_mfma<<<grid, 512, 0, stream>>>(apre, bpre, tlen, nlt, out);
}

// Round 6
// 45.127 us; speedup vs baseline: 12.0392x; 1.0091x over previous
//
#include <hip/hip_runtime.h>
#include <hip/hip_bf16.h>

typedef __attribute__((ext_vector_type(8)))  short bf16x8;
typedef __attribute__((ext_vector_type(16))) float f32x16;

#define I_N 256
#define T_N 256
#define L_N 32
#define E_N 128
#define P_N 49
#define TG  4   // texts per LDS buffer: 4 * 8 frags * 1KB = 32 KB/buffer

// ---- pre-pass: pack text(B) + image(A) into 32x32x16 MFMA fragment order ----
// B frag [t*8+ks][lane][8]: col l = lane&31 (token), k = ks*16 + (lane>>5)*8 + j
// A frag [i*16 + pt*8 + ks][lane][8]: patch = pt*32 + (lane&31), same k map.
__global__ __launch_bounds__(256) void pack_all(const float* __restrict__ txt,
                                                const float* __restrict__ img,
                                                unsigned short* __restrict__ bpre,
                                                unsigned short* __restrict__ apre) {
    const int bid = blockIdx.x;
    if (bid < 512) {                                 // ---- text: 256*8*64 threads
        int gid  = bid * 256 + threadIdx.x;
        int lane = gid & 63;
        int ks   = (gid >> 6) & 7;
        int t    = gid >> 9;
        int l    = lane & 31;
        int e0   = ks * 16 + (lane >> 5) * 8;
        const float* src = txt + (t * L_N + l) * E_N + e0;
        union { unsigned short u[8]; bf16x8 v; } o;
        #pragma unroll
        for (int j = 0; j < 8; ++j) {
            __hip_bfloat16 h = __float2bfloat16(src[j]);
            o.u[j] = *reinterpret_cast<unsigned short*>(&h);
        }
        ((bf16x8*)bpre)[gid] = o.v;
    } else {                                         // ---- image: 256*16*64 threads
        int gid   = (bid - 512) * 256 + threadIdx.x;
        int lane  = gid & 63;
        int ks    = (gid >> 6) & 7;
        int pt    = (gid >> 9) & 1;
        int i     = gid >> 10;
        int patch = pt * 32 + (lane & 31);
        int e0    = ks * 16 + (lane >> 5) * 8;
        const float* src = img + i * (E_N * P_N) + e0 * P_N + patch;
        union { unsigned short u[8]; bf16x8 v; } o;
        #pragma unroll
        for (int j = 0; j < 8; ++j) {
            float x = (patch < P_N) ? src[j * P_N] : 0.0f;
            __hip_bfloat16 h = __float2bfloat16(x);
            o.u[j] = *reinterpret_cast<unsigned short*>(&h);
        }
        ((bf16x8*)apre)[gid] = o.v;
    }
}

// ---- main kernel: grid (16,64), block 256 = 4 waves. Wave w -> image y*4+w. ----
// Texts t0..t0+15; B staged in LDS (double-buffered global_load_lds), shared by
// 4 waves. 2 blocks/CU -> one block's barriers/reduce hide under the other's MFMAs.
__global__ __launch_bounds__(256) void clip_mfma(
    const unsigned short* __restrict__ apre,
    const unsigned short* __restrict__ bpre,
    const int*   __restrict__ tlen,
    const float* __restrict__ nlt,
    float*       __restrict__ out) {

    __shared__ short sB[2][TG * 8 * 512];   // 2 x 32 KB

    const int wid  = threadIdx.x >> 6;
    const int lane = threadIdx.x & 63;
    const int i    = blockIdx.y * 4 + wid;
    const int t0   = blockIdx.x * 16;
    const float scale = expf(nlt[0]);
    const bool  lo32  = (lane < 32);

    // Pin image A-frags: 2 patch-tiles x 8 k-steps = 64 VGPRs, reused for 16 texts.
    bf16x8 af[2][8];
    const bf16x8* ap = (const bf16x8*)apre + (size_t)i * 16 * 64;
    #pragma unroll
    for (int pt = 0; pt < 2; ++pt)
        #pragma unroll
        for (int ks = 0; ks < 8; ++ks)
            af[pt][ks] = ap[(pt * 8 + ks) * 64 + lane];

    // Stage B-frags for texts [t0+g*TG, +TG): 32 frags, wave does 8.
    auto stage = [&](int buf, int g) {
        #pragma unroll
        for (int q = 0; q < 8; ++q) {
            int fl = wid * 8 + q;                   // 0..31 = t_in_group*8 + ks
            int t  = t0 + g * TG + (fl >> 3);
            int f  = fl & 7;
            const unsigned short* src = bpre + ((size_t)(t * 8 + f)) * 512 + lane * 8;
            short* dst = &sB[buf][fl * 512];
            __builtin_amdgcn_global_load_lds(
                (const __attribute__((address_space(1))) unsigned int*)(const void*)src,
                (__attribute__((address_space(3))) unsigned int*)(void*)dst, 16, 0, 0);
        }
    };

    // Reduce one text: max over 49 patches, sum over 32 tokens.
    // C: col = lane&31 (token), row = (reg&3)+8*(reg>>2)+4*(lane>>5) (patch in tile).
    // Tile1 (patches 32..63): valid (<=48) regs = 0..7 both halves, reg 8 lo-half only.
    auto reduceT = [&](f32x16 (&a)[2], int t) {
        float m = a[0][0];
        #pragma unroll
        for (int r = 1; r < 16; ++r) m = fmaxf(m, a[0][r]);
        #pragma unroll
        for (int r = 0; r < 8; ++r)  m = fmaxf(m, a[1][r]);
        m = fmaxf(m, lo32 ? a[1][8] : -INFINITY);
        m = fmaxf(m, __shfl_xor(m, 32));            // merge lane halves -> 49-patch max
        float s = m;
        #pragma unroll
        for (int off = 1; off <= 16; off <<= 1)
            s += __shfl_xor(s, off);                // sum over 32 token cols
        if (lane == 0) {
            float match = (s / (float)tlen[t]) * scale;
            out[i * T_N + t]             = match;   // logits_per_image [I][T]
            out[I_N * T_N + t * I_N + i] = match;   // logits_per_text  [T][I]
        }
    };

    bf16x8 bf[2][8];     // [parity][ks]
    f32x16 acc[2][2];    // [parity][pt]

    stage(0, 0);
    __syncthreads();

    #pragma unroll
    for (int tx = 0; tx < 16; ++tx) {     // full unroll -> all indices static
        const int p   = tx & 1;
        const int gg  = tx >> 2;
        const int txg = tx & 3;

        if ((tx & 3) == 0) {
            if (tx > 0) __syncthreads();  // buf (gg&1) staged; prev buf free
            if (gg + 1 < 4) stage((gg + 1) & 1, gg + 1);
        }

        const bf16x8* bfp = (const bf16x8*)&sB[gg & 1][0];
        #pragma unroll
        for (int ks = 0; ks < 8; ++ks)
            bf[p][ks] = bfp[(txg * 8 + ks) * 64 + lane];

        #pragma unroll
        for (int pt = 0; pt < 2; ++pt)
            #pragma unroll
            for (int r = 0; r < 16; ++r)
                acc[p][pt][r] = 0.0f;

        #pragma unroll
        for (int ks = 0; ks < 8; ++ks)
            #pragma unroll
            for (int pt = 0; pt < 2; ++pt)
                acc[p][pt] = __builtin_amdgcn_mfma_f32_32x32x16_bf16(
                    af[pt][ks], bf[p][ks], acc[p][pt], 0, 0, 0);

        if (tx > 0) reduceT(acc[1 - p], t0 + tx - 1);   // hides under tx's MFMA drain
    }
    reduceT(acc[1], t0 + 15);             // tx=15 had parity 1
}

extern "C" void kernel_launch(void* const* d_in, const int* in_sizes, int n_in,
                              void* d_out, int out_size, void* d_ws, size_t ws_size,
                              hipStream_t stream) {
    const float* img  = (const float*)d_in[0];
    const float* txt  = (const float*)d_in[1];
    const int*   tlen = (const int*)d_in[2];
    const float* nlt  = (const float*)d_in[3];
    float*       out  = (float*)d_out;

    unsigned short* bpre = (unsigned short*)d_ws;                       // 2 MB
    unsigned short* apre = (unsigned short*)((char*)d_ws + (2u << 20)); // 4 MB

    pack_all<<<1536, 256, 0, stream>>>(txt, img, bpre, apre);

    dim3 grid(16, 64);
    clip_mfma<<<grid, 256, 0, stream>>>(apre, bpre, tlen, nlt, out);
}